// Round 1
// baseline (161.514 us; speedup 1.0000x reference)
//
#include <hip/hip_runtime.h>
#include <hip/hip_fp16.h>

// MMD loss: N=4096, D=512, n_samples=8192, kernel_mul=2, kernel_num=5.
// result = (1/n^2) * sum_ij sigma_i sigma_j K(L2_ij),  sigma = +1 (src rows) / -1 (tgt rows)
// bandwidth = [2*ns*sum(sq) - 2*||colsum||^2] / (ns^2-ns) / 4;  scales bw*2^s, s=0..4

#define NS 8192
#define D_DIM 512
#define NTILE 64   // NS / 128

typedef _Float16 f16x8 __attribute__((ext_vector_type(8)));
typedef float f32x4 __attribute__((ext_vector_type(4)));

// ---------------- prep: f32 -> f16 convert + column sums ----------------
__global__ void prep_convert(const float* __restrict__ src, const float* __restrict__ tgt,
                             __half* __restrict__ Th, float* __restrict__ colsum) {
    int t = threadIdx.x;                 // 256 threads, thread covers cols 2t, 2t+1
    int r0 = blockIdx.x * 32;            // 256 blocks * 32 rows
    float c0 = 0.f, c1 = 0.f;
    for (int r = r0; r < r0 + 32; ++r) {
        const float* rowp = (r < 4096) ? (src + (size_t)r * D_DIM)
                                       : (tgt + (size_t)(r - 4096) * D_DIM);
        float2 v = *reinterpret_cast<const float2*>(rowp + 2 * t);
        __half h0 = __float2half(v.x), h1 = __float2half(v.y);
        __half2 hh; hh.x = h0; hh.y = h1;
        *reinterpret_cast<__half2*>(Th + (size_t)r * D_DIM + 2 * t) = hh;
        c0 += __half2float(h0); c1 += __half2float(h1);
    }
    atomicAdd(&colsum[2 * t], c0);
    atomicAdd(&colsum[2 * t + 1], c1);
}

// ---------------- row sums of squares (from converted values) ----------------
__global__ void prep_sq(const __half* __restrict__ Th, float* __restrict__ sq) {
    int wid = threadIdx.x >> 6, lane = threadIdx.x & 63;
    int r = blockIdx.x * 4 + wid;        // 2048 blocks * 4 waves
    const __half* rowp = Th + (size_t)r * D_DIM + lane * 8;
    int4 raw = *reinterpret_cast<const int4*>(rowp);
    const __half2* hp = reinterpret_cast<const __half2*>(&raw);
    float s = 0.f;
#pragma unroll
    for (int e = 0; e < 4; ++e) { float2 f = __half22float2(hp[e]); s += f.x * f.x + f.y * f.y; }
#pragma unroll
    for (int off = 32; off; off >>= 1) s += __shfl_xor(s, off, 64);
    if (lane == 0) sq[r] = s;
}

// ---------------- bandwidth scalars + zero accumulator ----------------
__global__ void compute_bw(const float* __restrict__ sq, const float* __restrict__ colsum,
                           float* __restrict__ cs5, double* __restrict__ acc) {
    __shared__ float red[256];
    int t = threadIdx.x;
    float s = 0.f;
    for (int i = t; i < NS; i += 256) s += sq[i];
    float c = 0.f;
    for (int i = t; i < D_DIM; i += 256) { float v = colsum[i]; c += v * v; }
    red[t] = s; __syncthreads();
    for (int off = 128; off; off >>= 1) { if (t < off) red[t] += red[t + off]; __syncthreads(); }
    float S = red[0]; __syncthreads();
    red[t] = c; __syncthreads();
    for (int off = 128; off; off >>= 1) { if (t < off) red[t] += red[t + off]; __syncthreads(); }
    if (t == 0) {
        float C = red[0];
        double sumL2 = 2.0 * (double)NS * (double)S - 2.0 * (double)C;
        double bw = sumL2 / ((double)NS * NS - (double)NS) / 4.0;  // / kernel_mul^(num//2)
        for (int s5 = 0; s5 < 5; ++s5)
            cs5[s5] = (float)(-1.4426950408889634 / (bw * (double)(1 << s5)));
        *acc = 0.0;
    }
}

// ---------------- main: triangular tiled gram + fused kernel-sum ----------------
__global__ __launch_bounds__(256, 2) void mmd_main(const __half* __restrict__ Th,
                                                   const float* __restrict__ sq,
                                                   const float* __restrict__ cs5,
                                                   double* __restrict__ acc_out) {
    __shared__ __half Ah[128 * 32];
    __shared__ __half Bh[128 * 32];
    __shared__ float wred[4];

    // decode upper-triangle tile (ti, tj), tj >= ti, from linear block id
    int b = blockIdx.x;
    int ti = 0, rem = b;
    while (rem >= NTILE - ti) { rem -= NTILE - ti; ++ti; }
    int tj = ti + rem;
    int ibase = ti * 128, jbase = tj * 128;
    float wgt = ((ti == tj) ? 1.f : 2.f) * (((ti < 32) == (tj < 32)) ? 1.f : -1.f);

    int tid = threadIdx.x;
    int wid = tid >> 6, lane = tid & 63;
    int wm = wid >> 1, wn = wid & 1;     // wave -> 64x64 quadrant

    f32x4 acc[4][4];
#pragma unroll
    for (int m = 0; m < 4; ++m)
#pragma unroll
        for (int n = 0; n < 4; ++n) acc[m][n] = f32x4{0.f, 0.f, 0.f, 0.f};

    for (int k0 = 0; k0 < D_DIM; k0 += 32) {
#pragma unroll
        for (int it = 0; it < 2; ++it) {
            int h = (tid + it * 256) * 8;        // half-element index into 128x32 tile
            int row = h >> 5, col = h & 31;
            __builtin_amdgcn_global_load_lds(
                (const __attribute__((address_space(1))) unsigned int*)(Th + (size_t)(ibase + row) * D_DIM + k0 + col),
                (__attribute__((address_space(3))) unsigned int*)(Ah + h), 16, 0, 0);
            __builtin_amdgcn_global_load_lds(
                (const __attribute__((address_space(1))) unsigned int*)(Th + (size_t)(jbase + row) * D_DIM + k0 + col),
                (__attribute__((address_space(3))) unsigned int*)(Bh + h), 16, 0, 0);
        }
        __syncthreads();

        f16x8 afr[4], bfr[4];
#pragma unroll
        for (int m = 0; m < 4; ++m)
            afr[m] = *reinterpret_cast<const f16x8*>(&Ah[(wm * 64 + m * 16 + (lane & 15)) * 32 + (lane >> 4) * 8]);
#pragma unroll
        for (int n = 0; n < 4; ++n)
            bfr[n] = *reinterpret_cast<const f16x8*>(&Bh[(wn * 64 + n * 16 + (lane & 15)) * 32 + (lane >> 4) * 8]);
#pragma unroll
        for (int m = 0; m < 4; ++m)
#pragma unroll
            for (int n = 0; n < 4; ++n)
                acc[m][n] = __builtin_amdgcn_mfma_f32_16x16x32_f16(afr[m], bfr[n], acc[m][n], 0, 0, 0);
        __syncthreads();
    }

    // epilogue: L2 -> 5x exp2 -> signed sum
    float sqi[16], sqj[4];
#pragma unroll
    for (int m = 0; m < 4; ++m)
#pragma unroll
        for (int r = 0; r < 4; ++r)
            sqi[m * 4 + r] = sq[ibase + wm * 64 + m * 16 + (lane >> 4) * 4 + r];
#pragma unroll
    for (int n = 0; n < 4; ++n)
        sqj[n] = sq[jbase + wn * 64 + n * 16 + (lane & 15)];
    float c[5];
#pragma unroll
    for (int s = 0; s < 5; ++s) c[s] = cs5[s];

    float ksum = 0.f;
#pragma unroll
    for (int m = 0; m < 4; ++m)
#pragma unroll
        for (int n = 0; n < 4; ++n)
#pragma unroll
            for (int r = 0; r < 4; ++r) {
                float L2 = sqi[m * 4 + r] + sqj[n] - 2.f * acc[m][n][r];
                ksum += __builtin_amdgcn_exp2f(L2 * c[0]) + __builtin_amdgcn_exp2f(L2 * c[1])
                      + __builtin_amdgcn_exp2f(L2 * c[2]) + __builtin_amdgcn_exp2f(L2 * c[3])
                      + __builtin_amdgcn_exp2f(L2 * c[4]);
            }
#pragma unroll
    for (int off = 32; off; off >>= 1) ksum += __shfl_xor(ksum, off, 64);
    if (lane == 0) wred[wid] = ksum;
    __syncthreads();
    if (tid == 0) {
        float tot = (wred[0] + wred[1]) + (wred[2] + wred[3]);
        atomicAdd(acc_out, (double)(tot * wgt));
    }
}

__global__ void finalize(const double* __restrict__ acc, float* __restrict__ out) {
    out[0] = (float)(*acc * (1.0 / (4096.0 * 4096.0)));
}

extern "C" void kernel_launch(void* const* d_in, const int* in_sizes, int n_in,
                              void* d_out, int out_size, void* d_ws, size_t ws_size,
                              hipStream_t stream) {
    (void)in_sizes; (void)n_in; (void)out_size; (void)ws_size;
    const float* src = (const float*)d_in[0];
    const float* tgt = (const float*)d_in[1];
    char* ws = (char*)d_ws;
    __half* Th    = (__half*)ws;                       // 8192*512*2 = 8,388,608 B
    float* sq     = (float*)(ws + 8388608);            // 8192*4 = 32 KB
    float* colsum = (float*)(ws + 8421376);            // 512*4 = 2 KB
    float* cs5    = (float*)(ws + 8423424);            // 5 floats
    double* acc   = (double*)(ws + 8423448);           // 8 B, 8-aligned
    float* out    = (float*)d_out;

    hipMemsetAsync(colsum, 0, D_DIM * sizeof(float), stream);
    hipLaunchKernelGGL(prep_convert, dim3(256), dim3(256), 0, stream, src, tgt, Th, colsum);
    hipLaunchKernelGGL(prep_sq, dim3(NS / 4), dim3(256), 0, stream, Th, sq);
    hipLaunchKernelGGL(compute_bw, dim3(1), dim3(256), 0, stream, sq, colsum, cs5, acc);
    hipLaunchKernelGGL(mmd_main, dim3((NTILE * (NTILE + 1)) / 2), dim3(256), 0, stream, Th, sq, cs5, acc);
    hipLaunchKernelGGL(finalize, dim3(1), dim3(1), 0, stream, acc, out);
}